// Round 5
// baseline (181.032 us; speedup 1.0000x reference)
//
#include <hip/hip_runtime.h>

#define HI 1440
#define WI 1920
#define NPIX (HI*WI)
#define EPSF 1e-8f

#define GCOLS 52            // valid output columns per wave
#define NG 37               // ceil(1920/52)
#define SROWS 15            // output rows per strip
#define NS 96               // 1440/15 exact
#define NWAVES (2*NG*NS)    // 2 targets x 3552 = 7104
#define PROWS 28            // raw rows per strip (mult of 7, >= SROWS+12)

typedef __fp16 h2 __attribute__((ext_vector_type(2)));

// ---------------- small 3x3 helpers (k_pre only) ----------------
__device__ __forceinline__ void mat3mul(const float* A, const float* B, float* C) {
#pragma unroll
  for (int i = 0; i < 3; ++i)
#pragma unroll
    for (int j = 0; j < 3; ++j)
      C[i*3+j] = A[i*3+0]*B[0+j] + A[i*3+1]*B[3+j] + A[i*3+2]*B[6+j];
}

__device__ void rodrigues_dev(const float* v, float* R) {
  float th = sqrtf(v[0]*v[0] + v[1]*v[1] + v[2]*v[2]) + 1e-12f;
  float kx = v[0]/th, ky = v[1]/th, kz = v[2]/th;
  float st = sinf(th), ct = cosf(th);
  float S[9] = {0.f,-kz,ky, kz,0.f,-kx, -ky,kx,0.f};
  float S2[9];
  mat3mul(S, S, S2);
#pragma unroll
  for (int i = 0; i < 9; ++i) R[i] = st*S[i] + (1.f-ct)*S2[i];
  R[0] += 1.f; R[4] += 1.f; R[8] += 1.f;
}

__global__ void k_pre(const float* __restrict__ focal, const float* __restrict__ aa,
                      const float* __restrict__ cen, float* __restrict__ mats) {
  if (threadIdx.x != 0 || blockIdx.x != 0) return;
  float f = focal[0];
  const float u0 = WI*0.5f - 0.5f;
  const float v0 = HI*0.5f - 0.5f;
  float K[9]  = {f,0.f,u0, 0.f,f,v0, 0.f,0.f,1.f};
  float Ki[9] = {1.f/f,0.f,-u0/f, 0.f,1.f/f,-v0/f, 0.f,0.f,1.f};
  float R1[9]; rodrigues_dev(aa, R1);
  float R1T[9];
  for (int i = 0; i < 3; ++i)
    for (int j = 0; j < 3; ++j) R1T[i*3+j] = R1[j*3+i];
  for (int t = 0; t < 2; ++t) {
    float Rt[9]; rodrigues_dev(aa + 3*(t+1), Rt);
    float A[9]; mat3mul(K, Rt, A);
    float Tm[9]; mat3mul(A, R1T, Tm);
    float B[9]; mat3mul(Tm, Ki, B);
    float Cd[3] = {cen[0]-cen[3*(t+1)+0], cen[1]-cen[3*(t+1)+1], cen[2]-cen[3*(t+1)+2]};
    float a0 = A[0]*Cd[0]+A[1]*Cd[1]+A[2]*Cd[2];
    float a1 = A[3]*Cd[0]+A[4]*Cd[1]+A[5]*Cd[2];
    float a2 = A[6]*Cd[0]+A[7]*Cd[1]+A[8]*Cd[2];
    float* M = mats + t*12;
    for (int i = 0; i < 9; ++i) M[i] = B[i];
    M[9] = a0; M[10] = a1; M[11] = a2;
  }
  mats[24] = f;
}

__device__ __forceinline__ float bilerp(const float* __restrict__ img, float px, float py) {
  float x0 = floorf(px), y0 = floorf(py);
  float wx = px - x0, wy = py - y0;
  float x1 = x0 + 1.f, y1 = y0 + 1.f;
  const float xmax = (float)(WI-1), ymax = (float)(HI-1);
  bool bx0 = (x0 >= 0.f) && (x0 <= xmax);
  bool bx1 = (x1 >= 0.f) && (x1 <= xmax);
  bool by0 = (y0 >= 0.f) && (y0 <= ymax);
  bool by1 = (y1 >= 0.f) && (y1 <= ymax);
  float v00 = 0.f, v10 = 0.f, v01 = 0.f, v11 = 0.f;
  if (bx0 && by0) v00 = img[(int)y0*WI + (int)x0];
  if (bx1 && by0) v10 = img[(int)y0*WI + (int)x1];
  if (bx0 && by1) v01 = img[(int)y1*WI + (int)x0];
  if (bx1 && by1) v11 = img[(int)y1*WI + (int)x1];
  return (1.f-wy)*((1.f-wx)*v00 + wx*v10) + wy*((1.f-wx)*v01 + wx*v11);
}

__device__ __forceinline__ float hsum7(float v, int ln) {
  float a = __shfl(v, ln-3, 64), b = __shfl(v, ln-2, 64), c = __shfl(v, ln-1, 64);
  float d = __shfl(v, ln+1, 64), e = __shfl(v, ln+2, 64), g = __shfl(v, ln+3, 64);
  return ((a + b) + (c + v)) + ((d + e) + g);
}

__device__ __forceinline__ h2 hsum7p(h2 v, int ln) {
  int vi = __builtin_bit_cast(int, v);
  h2 a = __builtin_bit_cast(h2, __shfl(vi, ln-3, 64));
  h2 b = __builtin_bit_cast(h2, __shfl(vi, ln-2, 64));
  h2 c = __builtin_bit_cast(h2, __shfl(vi, ln-1, 64));
  h2 d = __builtin_bit_cast(h2, __shfl(vi, ln+1, 64));
  h2 e = __builtin_bit_cast(h2, __shfl(vi, ln+2, 64));
  h2 g = __builtin_bit_cast(h2, __shfl(vi, ln+3, 64));
  return ((a + b) + (c + v)) + ((d + e) + g);
}

__device__ __forceinline__ float loadI(const float* __restrict__ p, int x, int y) {
  return (x >= 0 && x < WI && y >= 0 && y < HI) ? p[y*WI + x] : 0.f;
}

// Wave-streaming fused kernel, one wave = one (strip, target) pair.
// 64 raw columns (52 outputs), streams 28 raw rows; horizontal 7-sums via
// fp16-packed shuffles, vertical 7-sums via register rings. No LDS/barriers.
__global__ __launch_bounds__(256) void k_stream(const float* __restrict__ depth,
                                                const float* __restrict__ ref,
                                                const float* __restrict__ tgts,
                                                const float* __restrict__ mats,
                                                float* __restrict__ partials) {
  const int wid = blockIdx.x*4 + (threadIdx.x >> 6);
  if (wid >= NWAVES) return;
  const int ln = threadIdx.x & 63;
  const int t = wid & 1;
  const int rest = wid >> 1;
  const int g = rest % NG, st = rest / NG;
  const int R0 = st * SROWS;
  const int x = g*GCOLS - 6 + ln;
  const bool xok = (x >= 0) && (x < WI);

  const float f = mats[24];
  float M[12];
#pragma unroll
  for (int i = 0; i < 12; ++i) M[i] = mats[t*12 + i];
  const float* __restrict__ tgt = tgts + (size_t)t*NPIX;

  float dring[7], rring[7], wring[7];
  float Hr[7], Hw[7];
  float Qrr[7], Qrt[7], Qtt[7];
#pragma unroll
  for (int k = 0; k < 7; ++k) {
    dring[k]=0.f; rring[k]=0.f; wring[k]=0.f;
    Hr[k]=0.f; Hw[k]=0.f;
    Qrr[k]=0.f; Qrt[k]=0.f; Qtt[k]=0.f;
  }
  float Sr=0.f, Sw=0.f;
  float Vrr=0.f, Vrt=0.f, Vtt=0.f;
  float acc_s=0.f, acc_c=0.f;

  // prime depth ring: rows R0-7 (slot 6) and R0-6 (slot 0)
  dring[6] = loadI(depth, x, R0-7);
  dring[0] = loadI(depth, x, R0-6);

  for (int ib = 0; ib < PROWS; ib += 7) {
#pragma unroll
    for (int j = 0; j < 7; ++j) {
      const int y = R0 - 6 + ib + j;
      dring[(j+1)%7] = loadI(depth, x, y+1);

      // ---- warp + gather at (x,y) ----
      float r = 0.f, w = 0.f;
      if (xok && y >= 0 && y < HI) {
        const int gidx = y*WI + x;
        r = ref[gidx];
        float d  = dring[j];
        float dm = (x > 0)    ? depth[gidx-1] : 0.f;
        float dp = (x < WI-1) ? depth[gidx+1] : 0.f;
        float du = 0.5f*(dp - dm);
        float dv = 0.5f*(dring[(j+1)%7] - dring[(j+6)%7]);
        float fx = (float)x, fy = (float)y;
        float nx = f*du, ny = f*dv;
        float nz = (960.f - fx)*du + (720.f - fy)*dv - d;
        float nn = sqrtf(nx*nx + ny*ny + nz*nz) + EPSF;
        float wsc = 1.f/(nn*(d + EPSF));
        float px = (fx - 959.5f)/f, py = (fy - 719.5f)/f;
        float sv = (nx*px + ny*py + nz)*wsc;
        float a0 = M[0]*fx + M[1]*fy + M[2] + M[9]*sv;
        float a1 = M[3]*fx + M[4]*fy + M[5] + M[10]*sv;
        float a2 = M[6]*fx + M[7]*fy + M[8] + M[11]*sv;
        float iz = 1.f/(a2 + EPSF);
        w = bilerp(tgt, a0*iz, a1*iz);
      }
      rring[j] = r;
      wring[j] = w;

      // ---- horizontal 7-sums of raw planes (fp16-packed) ----
      h2 hp = hsum7p(__builtin_amdgcn_cvt_pkrtz(r, w), ln);
      float hr = (float)hp.x, hw = (float)hp.y;

      // ---- vertical running box sums; box complete at yc = y-3 ----
      Sr += hr; Sw += hw;
      const float Br = Sr, Bw = Sw;
      Sr -= Hr[(j+1)%7]; Sw -= Hw[(j+1)%7];
      Hr[j] = hr; Hw[j] = hw;

      // ---- centered values at row yc ----
      const int yc = y - 3;
      float cr = 0.f, ct = 0.f;
      if (xok && yc >= 0 && yc < HI) {
        cr = rring[(j+4)%7] - Br*(1.f/49.f);
        ct = wring[(j+4)%7] - Bw*(1.f/49.f);
      }

      // ---- product horizontal 7-sums ----
      float prr = hsum7(cr*cr, ln);
      h2 q = hsum7p(__builtin_amdgcn_cvt_pkrtz(cr*ct, ct*ct), ln);
      float hrt = (float)q.x, htt = (float)q.y;

      // ---- vertical running window sums; window complete at yo = y-6 ----
      Vrr += prr; Vrt += hrt; Vtt += htt;

      const int yo = y - 6;
      if (yo >= R0 && yo < R0 + SROWS && ln >= 6 && ln <= 57 && x < WI) {
        const float wv = wring[(j+1)%7];   // raw w at row yo
        if (wv != 0.f) {
          const float inv49 = 1.f/49.f;
          float zm = (Vrt*inv49) * rsqrtf((Vrr*inv49)*(Vtt*inv49) + EPSF);
          acc_s += zm; acc_c += 1.f;
        }
      }

      Vrr -= Qrr[(j+5)%7]; Vrt -= Qrt[(j+5)%7]; Vtt -= Qtt[(j+5)%7];
      Qrr[(j+4)%7] = prr; Qrt[(j+4)%7] = hrt; Qtt[(j+4)%7] = htt;
    }
  }

  // ---- wave reduce, one partial pair per wave ----
#pragma unroll
  for (int off = 32; off > 0; off >>= 1) {
    acc_s += __shfl_down(acc_s, off, 64);
    acc_c += __shfl_down(acc_c, off, 64);
  }
  if (ln == 0) { partials[2*wid] = acc_s; partials[2*wid+1] = acc_c; }
}

__global__ __launch_bounds__(256) void k_final(const float* __restrict__ partials, int nb,
                                               float* __restrict__ out) {
  float s = 0.f, c = 0.f;
  for (int i = threadIdx.x; i < nb; i += 256) {
    s += partials[2*i];
    c += partials[2*i+1];
  }
#pragma unroll
  for (int off = 32; off > 0; off >>= 1) {
    s += __shfl_down(s, off, 64);
    c += __shfl_down(c, off, 64);
  }
  __shared__ float red[8];
  int tid = threadIdx.x;
  if ((tid & 63) == 0) { red[(tid>>6)*2] = s; red[(tid>>6)*2+1] = c; }
  __syncthreads();
  if (tid == 0) {
    float S = red[0]+red[2]+red[4]+red[6];
    float C = red[1]+red[3]+red[5]+red[7];
    float mean = S / fmaxf(C, 1.f);
    out[0] = (C > 0.f) ? 0.5f*(1.f - mean) : 0.f;
  }
}

extern "C" void kernel_launch(void* const* d_in, const int* in_sizes, int n_in,
                              void* d_out, int out_size, void* d_ws, size_t ws_size,
                              hipStream_t stream) {
  const float* focal  = (const float*)d_in[0];
  const float* aa     = (const float*)d_in[1];
  const float* cen    = (const float*)d_in[2];
  const float* ref    = (const float*)d_in[3];
  const float* depth  = (const float*)d_in[4];
  const float* tgts   = (const float*)d_in[5];
  float* out = (float*)d_out;

  float* wsf      = (float*)d_ws;
  float* mats     = wsf;              // 32
  float* partials = wsf + 32;         // 2 * NWAVES

  k_pre<<<1, 64, 0, stream>>>(focal, aa, cen, mats);
  k_stream<<<(NWAVES + 3)/4, 256, 0, stream>>>(depth, ref, tgts, mats, partials);
  k_final<<<1, 256, 0, stream>>>(partials, NWAVES, out);
}